// Round 7
// baseline (218.290 us; speedup 1.0000x reference)
//
#include <hip/hip_runtime.h>

typedef unsigned short u16;
typedef short short8 __attribute__((ext_vector_type(8)));
typedef float floatx4 __attribute__((ext_vector_type(4)));
typedef u16 u16x4 __attribute__((ext_vector_type(4)));
typedef u16 u16x8 __attribute__((ext_vector_type(8)));

#define DEVI __device__ __forceinline__

DEVI u16 f2bf(float x) {
    union { float f; unsigned u; } c; c.f = x;
    unsigned u = c.u;
    u += 0x7fffu + ((u >> 16) & 1u);   // RNE
    return (u16)(u >> 16);
}
DEVI float bf2f(u16 h) {
    union { unsigned u; float f; } c; c.u = ((unsigned)h) << 16;
    return c.f;
}

DEVI void gload_lds16(const void* g, void* l) {
    auto gp = (const __attribute__((address_space(1))) unsigned*)(unsigned long long)g;
    auto lp = (__attribute__((address_space(3))) unsigned*)(unsigned)(unsigned long long)l;
    __builtin_amdgcn_global_load_lds(gp, lp, 16, 0, 0);
}

// ---------------- fused GroupNorm: single global read, stats + apply in regs ----------------
__global__ __launch_bounds__(256) void gn_fused_kernel(const float* __restrict__ x,
                                                       const float* __restrict__ w,
                                                       const float* __restrict__ bb,
                                                       u16* __restrict__ h) {
    const int bg = blockIdx.x;           // b*32+g
    const int b = bg >> 5, g = bg & 31;
    const float* xg = x + (long long)bg * 16384;
    const int n0 = threadIdx.x * 4;

    float4 xv[16];
    float s = 0.f, s2 = 0.f;
    #pragma unroll
    for (int cc = 0; cc < 16; cc++) {
        xv[cc] = *(const float4*)&xg[cc * 1024 + n0];
        s  += xv[cc].x + xv[cc].y + xv[cc].z + xv[cc].w;
        s2 += xv[cc].x*xv[cc].x + xv[cc].y*xv[cc].y + xv[cc].z*xv[cc].z + xv[cc].w*xv[cc].w;
    }
    #pragma unroll
    for (int m = 1; m < 64; m <<= 1) { s += __shfl_xor(s, m, 64); s2 += __shfl_xor(s2, m, 64); }
    __shared__ float rs[4], rq[4];
    if ((threadIdx.x & 63) == 0) { rs[threadIdx.x >> 6] = s; rq[threadIdx.x >> 6] = s2; }
    __syncthreads();
    float mean = (rs[0] + rs[1] + rs[2] + rs[3]) * (1.f / 16384.f);
    float var  = (rq[0] + rq[1] + rq[2] + rq[3]) * (1.f / 16384.f) - mean * mean;
    float rstd = rsqrtf(var + 1e-5f);

    u16x8 o[4][2];
    #pragma unroll
    for (int cc = 0; cc < 16; cc++) {
        int c = g * 16 + cc;
        float sc = w[c] * rstd;
        float sh = bb[c] - mean * sc;
        o[0][cc >> 3][cc & 7] = f2bf(xv[cc].x * sc + sh);
        o[1][cc >> 3][cc & 7] = f2bf(xv[cc].y * sc + sh);
        o[2][cc >> 3][cc & 7] = f2bf(xv[cc].z * sc + sh);
        o[3][cc >> 3][cc & 7] = f2bf(xv[cc].w * sc + sh);
    }
    u16* hb = h + ((long long)b * 1024 + n0) * 512 + g * 16;
    #pragma unroll
    for (int k = 0; k < 4; k++) {
        *(u16x8*)&hb[(long long)k * 512]     = o[k][0];
        *(u16x8*)&hb[(long long)k * 512 + 8] = o[k][1];
    }
}

// ---------------- both weight conversions in one launch ----------------
__global__ __launch_bounds__(256) void wconv_kernel(const float* __restrict__ w1, u16* __restrict__ o1,
                                                    const float* __restrict__ w2, u16* __restrict__ o2) {
    int i = blockIdx.x * 256 + threadIdx.x;   // of 262144 float4 slots
    const float* src; u16* dst; int j;
    if (i < 196608) { src = w1; dst = o1; j = i; }
    else            { src = w2; dst = o2; j = i - 196608; }
    float4 v = *(const float4*)&src[j * 4];
    u16x4 p; p[0] = f2bf(v.x); p[1] = f2bf(v.y); p[2] = f2bf(v.z); p[3] = f2bf(v.w);
    *(u16x4*)&dst[j * 4] = p;
}

// ---------------- invl[z][n] = 1 / sum_kb psum[z][kb][n]  (4 key-blocks of 256) ----------------
__global__ __launch_bounds__(256) void lreduce_kernel(const float* __restrict__ ps,
                                                      float* __restrict__ invl) {
    int i = blockIdx.x * 256 + threadIdx.x;   // 16384 = z*1024+n
    int z = i >> 10, n = i & 1023;
    float l = 0.f;
    #pragma unroll
    for (int kb = 0; kb < 4; kb++) l += ps[((z * 4 + kb) << 10) + n];
    invl[i] = 1.f / l;
}

// =====================================================================================
// 256x256 8-phase GEMM, BK=64, 512 thr. kk-split LDS ([2kk][128r][32e], 64-B rows) +
// 2-bit slot swizzle -> 2-way residual bank conflicts (free). Operand-held phase order
// (A0B0)(A0B1)(A1B0)(A1B1): 24 ds_read_b128/wave/tile. Counted vmcnt, setprio MFMA.
// C = A @ B^T (both row-major [rows][K]); bf16 out = (EXPSTATS ? exp(acc*scale) : acc*scale)
// EXPSTATS also emits per-row partial sum of the stored bf16 E per 256-col key block.
// =====================================================================================
#define VMCNT(N) do { asm volatile("s_waitcnt vmcnt(" #N ")" ::: "memory"); \
                      __builtin_amdgcn_sched_barrier(0); } while (0)
#define LGKM0 do { asm volatile("s_waitcnt lgkmcnt(0)" ::: "memory"); \
                   __builtin_amdgcn_sched_barrier(0); } while (0)
#define BAR __builtin_amdgcn_s_barrier()

template <bool EXPSTATS, bool AFFINE>
__global__ __launch_bounds__(512, 1)
void gemm256_kernel(const u16* __restrict__ A, const u16* __restrict__ Bt,
                    u16* __restrict__ C, float* __restrict__ aux,
                    float scale, int lda, int ldb, int ldc,
                    long long sA, long long sB, long long sC, int K) {
    int bx, by, bz;
    if (AFFINE) {   // 256 blocks: batch z on XCD z&7
        const int lid = blockIdx.x;
        const int slot = lid >> 3;
        bz = (lid & 7) + 8 * (slot >> 4);
        const int w = slot & 15;
        bx = w & 3; by = w >> 2;
    } else { bx = blockIdx.x; by = blockIdx.y; bz = 0; }

    const int t    = threadIdx.x;
    const int lane = t & 63;
    const int wave = t >> 6;          // 0..7
    const int wm   = wave >> 2;       // 0..1
    const int wn   = wave & 3;        // 0..3
    const int quad = lane >> 4, lrow = lane & 15;
    const int m0 = by * 256, n0 = bx * 256;

    // A: [2buf][2half][2kk][128 rows][32 u16] = 32768 u16 ; B same at +32768. 128 KB total.
    __shared__ __align__(16) u16 smem[65536];

    const int NT = K >> 6;

    floatx4 acc[8][4];
    #pragma unroll
    for (int i = 0; i < 8; i++)
        #pragma unroll
        for (int j = 0; j < 4; j++)
            #pragma unroll
            for (int r = 0; r < 4; r++) acc[i][j][r] = 0.f;

    // staging: thread t -> (row = t>>2, slot = t&3) of one kk-region; linear LDS dest
    // t*16B; global source column pre-swizzled (slot ^= (row>>1)&3).
    const int srow  = t >> 2;                                   // 0..127
    const int skoff = ((t & 3) * 8) ^ ((((t >> 3)) & 3) << 3);  // elems within 32 (kk-rel)
    const u16* Ab = A  + (long long)bz * sA + (long long)(m0 + srow) * lda + skoff;
    const u16* Bb = Bt + (long long)bz * sB + (long long)(n0 + srow) * ldb + skoff;

#define STGA(BUF, HALF, KT) do { \
    const u16* g_ = Ab + (long long)((HALF) * 128) * lda + (KT) * 64; \
    gload_lds16(g_,      smem + ((BUF)*2 + (HALF)) * 8192 + t * 8); \
    gload_lds16(g_ + 32, smem + ((BUF)*2 + (HALF)) * 8192 + 4096 + t * 8); \
} while (0)
#define STGB(BUF, HALF, KT) do { \
    const u16* g_ = Bb + (long long)((HALF) * 128) * ldb + (KT) * 64; \
    gload_lds16(g_,      smem + 32768 + ((BUF)*2 + (HALF)) * 8192 + t * 8); \
    gload_lds16(g_ + 32, smem + 32768 + ((BUF)*2 + (HALF)) * 8192 + 4096 + t * 8); \
} while (0)

    const int rswz = (lrow >> 1) & 3;       // row bits 1-2 (lane-varying part)
    const int arow = wm * 64 + lrow;
    const int brow = wn * 32 + lrow;
#define AIDX(BUF, QA, i, kk) (((BUF)*2 + (QA)) * 8192 + (kk) * 4096 + (arow + (i)*16) * 32 + ((quad ^ rswz) << 3))
#define BIDX(BUF, QB, j, kk) (32768 + ((BUF)*2 + (QB)) * 8192 + (kk) * 4096 + (brow + (j)*16) * 32 + ((quad ^ rswz) << 3))

    short8 pa[4][2], pb0[2][2], pb1[2][2];
#define LOADA(BUF, QA) do { _Pragma("unroll") for (int i = 0; i < 4; ++i) { \
    pa[i][0] = *(const short8*)&smem[AIDX(BUF, QA, i, 0)]; \
    pa[i][1] = *(const short8*)&smem[AIDX(BUF, QA, i, 1)]; } } while (0)
#define LOADB(BUF, QB, PB) do { _Pragma("unroll") for (int j = 0; j < 2; ++j) { \
    PB[j][0] = *(const short8*)&smem[BIDX(BUF, QB, j, 0)]; \
    PB[j][1] = *(const short8*)&smem[BIDX(BUF, QB, j, 1)]; } } while (0)
#define MM(QA, QB, PB) do { __builtin_amdgcn_s_setprio(1); \
    _Pragma("unroll") for (int i = 0; i < 4; ++i) \
        _Pragma("unroll") for (int j = 0; j < 2; ++j) { \
            acc[(QA)*4 + i][(QB)*2 + j] = __builtin_amdgcn_mfma_f32_16x16x32_bf16( \
                pa[i][0], PB[j][0], acc[(QA)*4 + i][(QB)*2 + j], 0, 0, 0); \
            acc[(QA)*4 + i][(QB)*2 + j] = __builtin_amdgcn_mfma_f32_16x16x32_bf16( \
                pa[i][1], PB[j][1], acc[(QA)*4 + i][(QB)*2 + j], 0, 0, 0); } \
    __builtin_amdgcn_s_setprio(0); } while (0)

    // prologue: tile0 complete, full drain + barrier (cross-wave-safe start), then tile1-h0
    STGA(0, 0, 0); STGB(0, 0, 0); STGA(0, 1, 0); STGB(0, 1, 0);
    asm volatile("s_waitcnt vmcnt(0)" ::: "memory");
    BAR;
    STGA(1, 0, 1); STGB(1, 0, 1);

    // steady: reads p1:{A0,B0} p2:{B1} p3:{A1} p4:{} ; stages p1:A(nb,h1) p2:B(nb,h1)
    // p3:{A,B}(b,h0,tau+2). vmcnt ledger: p1 needs p3(tau-2) -> 8; p2 needs p2(tau-1) -> 6.
    for (int tau = 0; tau < NT - 1; ++tau) {
        const int buf = tau & 1, nbuf = buf ^ 1;
        const bool s2 = tau < NT - 2;
        VMCNT(8);
        LOADA(buf, 0); LOADB(buf, 0, pb0);
        STGA(nbuf, 1, tau + 1);
        BAR; LGKM0; MM(0, 0, pb0); BAR;
        VMCNT(6);
        LOADB(buf, 1, pb1);
        STGB(nbuf, 1, tau + 1);
        BAR; LGKM0; MM(0, 1, pb1); BAR;
        LOADA(buf, 1);
        if (s2) { STGA(buf, 0, tau + 2); STGB(buf, 0, tau + 2); }
        BAR; LGKM0; MM(1, 0, pb0); BAR;
        MM(1, 1, pb1);
    }
    {   // tail tile NT-1: residual counts 4 / 0
        const int buf = (NT - 1) & 1;
        VMCNT(4);
        LOADA(buf, 0); LOADB(buf, 0, pb0);
        BAR; LGKM0; MM(0, 0, pb0); BAR;
        VMCNT(0);
        LOADB(buf, 1, pb1);
        BAR; LGKM0; MM(0, 1, pb1); BAR;
        LOADA(buf, 1);
        BAR; LGKM0; MM(1, 0, pb0); BAR;
        MM(1, 1, pb1);
    }

    // ---------------- epilogue: 4 slabs of 64 rows x 256 cols through LDS ----------------
    const int ST2 = 272;
    const int erow = t >> 3;            // 0..63
    const int ec0  = (t & 7) * 32;
    #pragma unroll
    for (int s = 0; s < 4; ++s) {
        if (s) __syncthreads();
        if (wm == (s & 1)) {
            const int qa = s >> 1;
            #pragma unroll
            for (int i = 0; i < 4; ++i)
                #pragma unroll
                for (int cf = 0; cf < 4; ++cf) {
                    const int col = (cf >> 1) * 128 + wn * 32 + (cf & 1) * 16 + lrow;
                    #pragma unroll
                    for (int r = 0; r < 4; ++r) {
                        float v = acc[qa * 4 + i][cf][r] * scale;
                        if (EXPSTATS) v = __expf(v);
                        smem[(i * 16 + quad * 4 + r) * ST2 + col] = f2bf(v);
                    }
                }
        }
        __syncthreads();
        u16x8 y[4];
        #pragma unroll
        for (int kq = 0; kq < 4; ++kq) y[kq] = *(u16x8*)&smem[erow * ST2 + ec0 + kq * 8];
        u16* Cp = C + (long long)bz * sC + (long long)(m0 + s * 64 + erow) * ldc + n0 + ec0;
        #pragma unroll
        for (int kq = 0; kq < 4; ++kq) *(u16x8*)(Cp + kq * 8) = y[kq];
        if (EXPSTATS) {
            float ls = 0.f;
            #pragma unroll
            for (int kq = 0; kq < 4; ++kq)
                #pragma unroll
                for (int e = 0; e < 8; ++e) ls += bf2f(y[kq][e]);
            ls += __shfl_xor(ls, 1, 64);
            ls += __shfl_xor(ls, 2, 64);
            ls += __shfl_xor(ls, 4, 64);
            if ((t & 7) == 0)
                aux[((long long)(bz * 4 + bx)) * 1024 + m0 + s * 64 + erow] = ls;
        }
    }
#undef STGA
#undef STGB
#undef AIDX
#undef BIDX
#undef LOADA
#undef LOADB
#undef MM
}

// ---------------- TN GEMM, 128x128 tile, BK=64 (QKV + out projections) ----------------
// MODE 2: bf16 transposed out C0[n][m] + bias[m]
// MODE 3: fp32 out = acc*invl[n] + bias[m] + res   (B is plain bf16 DMA, e.g. E)
// NX>0: 1D launch, decoded so batch z runs on XCD z&7.
template <int MODE, int NX, int NY, bool STATS, int MINW = 3>
__global__ __launch_bounds__(256, MINW)
void gemm_bt_kernel(const u16* __restrict__ A, const u16* __restrict__ Bt,
                    void* __restrict__ C0,
                    const float* __restrict__ bias, const float* __restrict__ res,
                    float* __restrict__ aux,
                    float scale, int lda, int ldb, int ldc,
                    long long sA, long long sB, long long sC, long long sR, int K) {
    int bx, by, bz;
    if (NX > 0) {
        const int lid  = blockIdx.x;
        const int xcd  = lid & 7;
        const int slot = lid >> 3;
        const int per  = NX * NY;
        const int j    = slot / per;
        const int w    = slot - j * per;
        bz = xcd + 8 * j;
        bx = w % NX;
        by = w / NX;
    } else {
        bx = blockIdx.x; by = blockIdx.y; bz = blockIdx.z;
    }
    const int t    = threadIdx.x;
    const int lane = t & 63;
    const int wave = t >> 6;
    const int m0   = by * 128;
    const int n0   = bx * 128;
    A  += (long long)bz * sA;
    Bt += (long long)bz * sB;

    __shared__ __align__(16) u16 smem[16384];   // 32 KB: A[2][128][32] | B[2][128][32]
    u16* As = smem;
    u16* Bs = smem + 8192;

    const int wm = wave >> 1, wn = wave & 1;
    const int quad = lane >> 4, lrow = lane & 15;

    floatx4 acc[4][4];
    #pragma unroll
    for (int i = 0; i < 4; i++)
        #pragma unroll
        for (int j = 0; j < 4; j++)
            #pragma unroll
            for (int r = 0; r < 4; r++) acc[i][j][r] = 0.f;

    const int rowA = t >> 2;
    const int kch  = (t & 3) * 8;
    const u16* Ag = A  + (long long)(m0 + rowA) * lda + kch;
    const u16* Bg = Bt + (long long)(n0 + rowA) * ldb + kch;
    u16* Al = &As[t * 8];
    u16* Bl = &Bs[t * 8];
    const long long a64 = (long long)64 * lda;
    const long long b64 = (long long)64 * ldb;

    for (int k0 = 0; k0 < K; k0 += 64) {
        gload_lds16(Ag + k0,            Al);
        gload_lds16(Ag + k0 + a64,      Al + 2048);
        gload_lds16(Ag + k0 + 32,       Al + 4096);
        gload_lds16(Ag + k0 + 32 + a64, Al + 6144);
        gload_lds16(Bg + k0,            Bl);
        gload_lds16(Bg + k0 + b64,      Bl + 2048);
        gload_lds16(Bg + k0 + 32,       Bl + 4096);
        gload_lds16(Bg + k0 + 32 + b64, Bl + 6144);
        __syncthreads();
        #pragma unroll
        for (int kk = 0; kk < 2; kk++) {
            short8 af[4], bfr[4];
            #pragma unroll
            for (int i = 0; i < 4; i++)
                af[i] = *(const short8*)&As[kk*4096 + (wm*64 + i*16 + lrow)*32 + quad*8];
            #pragma unroll
            for (int j = 0; j < 4; j++)
                bfr[j] = *(const short8*)&Bs[kk*4096 + (wn*64 + j*16 + lrow)*32 + quad*8];
            #pragma unroll
            for (int i = 0; i < 4; i++)
                #pragma unroll
                for (int j = 0; j < 4; j++)
                    acc[i][j] = __builtin_amdgcn_mfma_f32_16x16x32_bf16(af[i], bfr[j], acc[i][j], 0, 0, 0);
        }
        __syncthreads();
    }
    // smem free from here

    const int ST = 136;  // u16 row stride (272 B = 17*16)

    if (MODE == 2) {
        #pragma unroll
        for (int p = 0; p < 4; p++) {
            if (p) __syncthreads();
            if (wn == (p >> 1)) {
                #pragma unroll
                for (int jj = 0; jj < 2; jj++) {
                    const int j = (p & 1) * 2 + jj;
                    const int row = jj * 16 + lrow;
                    #pragma unroll
                    for (int i = 0; i < 4; i++) {
                        const int mmL = wm * 64 + i * 16 + quad * 4;
                        u16x4 pk;
                        #pragma unroll
                        for (int r = 0; r < 4; r++)
                            pk[r] = f2bf(acc[i][j][r] + bias[m0 + mmL + r]);
                        *(u16x4*)&smem[row * ST + mmL] = pk;
                    }
                }
            }
            __syncthreads();
            const int rr = t >> 3, cc = (t & 7) * 16;
            u16x8 a0 = *(u16x8*)&smem[rr * ST + cc];
            u16x8 a1 = *(u16x8*)&smem[rr * ST + cc + 8];
            u16* Cp = (u16*)C0 + (long long)(n0 + p * 32 + rr) * ldc + m0 + cc;
            *(u16x8*)Cp = a0;
            *(u16x8*)(Cp + 8) = a1;
        }
    } else {
        // MODE 3: fp32 out = acc*invl[col] + bias[row] + res
        float* smf = (float*)smem;
        const int SF = 132;
        float* C = (float*)C0 + (long long)bz * sC;
        const float* rz = res + (long long)bz * sR;
        const float* il = aux + (long long)bz * 1024;
        #pragma unroll
        for (int p = 0; p < 8; p++) {
            if (p) __syncthreads();
            if (wm == (p >> 2)) {
                const int i = p & 3;
                #pragma unroll
                for (int j = 0; j < 4; j++) {
                    const int cB = wn * 64 + j * 16 + lrow;
                    #pragma unroll
                    for (int r = 0; r < 4; r++)
                        smf[(quad * 4 + r) * SF + cB] = acc[i][j][r];
                }
            }
            __syncthreads();
            const int rr = t >> 4, cc = (t & 15) * 8;
            const float bsv = bias[m0 + p * 16 + rr];
            float4 il0 = *(const float4*)&il[n0 + cc];
            float4 il1 = *(const float4*)&il[n0 + cc + 4];
            const long long gro = (long long)(m0 + p * 16 + rr) * ldc + n0 + cc;
            float4 rv0 = *(const float4*)&rz[gro];
            float4 rv1 = *(const float4*)&rz[gro + 4];
            float4 ov0, ov1;
            ov0.x = smf[rr*SF + cc + 0] * il0.x + bsv + rv0.x;
            ov0.y = smf[rr*SF + cc + 1] * il0.y + bsv + rv0.y;
            ov0.z = smf[rr*SF + cc + 2] * il0.z + bsv + rv0.z;
            ov0.w = smf[rr*SF + cc + 3] * il0.w + bsv + rv0.w;
            ov1.x = smf[rr*SF + cc + 4] * il1.x + bsv + rv1.x;
            ov1.y = smf[rr*SF + cc + 5] * il1.y + bsv + rv1.y;
            ov1.z = smf[rr*SF + cc + 6] * il1.z + bsv + rv1.z;
            ov1.w = smf[rr*SF + cc + 7] * il1.w + bsv + rv1.w;
            *(float4*)&C[gro]     = ov0;
            *(float4*)&C[gro + 4] = ov1;
        }
    }
}

extern "C" void kernel_launch(void* const* d_in, const int* in_sizes, int n_in,
                              void* d_out, int out_size, void* d_ws, size_t ws_size,
                              hipStream_t stream) {
    (void)in_sizes; (void)n_in; (void)out_size; (void)ws_size;
    const float* x     = (const float*)d_in[0];
    const float* gn_w  = (const float*)d_in[1];
    const float* gn_b  = (const float*)d_in[2];
    const float* qkv_w = (const float*)d_in[3];
    const float* qkv_b = (const float*)d_in[4];
    const float* out_w = (const float*)d_in[5];
    const float* out_b = (const float*)d_in[6];
    float* out = (float*)d_out;

    char* ws = (char*)d_ws;
    u16*  h_t   = (u16*)ws;  ws += (size_t)16*1024*512*2;    // 16 MB h[b][n][c]
    u16*  qkv_t = (u16*)ws;  ws += (size_t)16*1024*1536*2;   // 48 MB qkv[b*n][1536]
    u16*  vprm  = (u16*)ws;  ws += (size_t)512*16384*2;      // 16 MB V' = Wo V^T : [c_out][b*1024+n]
    u16*  E     = (u16*)ws;  ws += (size_t)16*1024*1024*2;   // 32 MB E[b][n][m] = exp(S*scale), bf16
    u16*  wq    = (u16*)ws;  ws += (size_t)1536*512*2;
    u16*  wo    = (u16*)ws;  ws += (size_t)512*512*2;
    float* psum = (float*)ws; ws += (size_t)16*8*1024*4;     // partial sum(E) per key-block (4 used)
    float* invl = (float*)ws; ws += (size_t)16*1024*4;       // 1/rowsum

    wconv_kernel<<<1024, 256, 0, stream>>>(qkv_w, wq, out_w, wo);
    gn_fused_kernel<<<512, 256, 0, stream>>>(x, gn_w, gn_b, h_t);

    // QKV: M=1536, Nn=16384, K=512 ; all transposed -> qkv_t[bn][1536] + bias
    gemm_bt_kernel<2, 0, 0, false, 3><<<dim3(128, 12, 1), 256, 0, stream>>>(
        wq, h_t, qkv_t, qkv_b, nullptr, nullptr, 1.0f,
        512, 512, 1536, 0, 0, 0, 0, 512);

    // V' = Wo @ V^T : M=512(c_out), Nn=16384(bn), K=512(c_in) ; 256^2 8-phase
    gemm256_kernel<false, false><<<dim3(64, 2, 1), 512, 0, stream>>>(
        wo, qkv_t + 1024, vprm, nullptr, 1.0f,
        512, 1536, 16384, 0, 0, 0, 512);

    // E = exp(q k^T * scale) : per batch M=Nn=1024, K=512 ; 256^2 8-phase, XCD-affine,
    // stores E + per-row partial sum(E) per 256-key block
    gemm256_kernel<true, true><<<256, 512, 0, stream>>>(
        qkv_t, qkv_t + 512, E, psum, 0.044194173824159216f,
        1536, 1536, 1024,
        (long long)1024*1536, (long long)1024*1536, (long long)1024*1024, 512);

    lreduce_kernel<<<64, 256, 0, stream>>>(psum, invl);

    // out = vprm ⊗ E * invl + out_b + x : M=512, Nn=1024(n), K=1024(m) ; XCD-affine, plain DMA B
    gemm_bt_kernel<3, 8, 4, false, 3><<<512, 256, 0, stream>>>(
        vprm, E, out, out_b, x, invl, 1.0f,
        16384, 1024, 1024,
        1024, (long long)1024*1024, (long long)512*1024, (long long)512*1024, 1024);
}

// Round 8
// 205.839 us; speedup vs baseline: 1.0605x; 1.0605x over previous
//
#include <hip/hip_runtime.h>

typedef unsigned short u16;
typedef short short8 __attribute__((ext_vector_type(8)));
typedef float floatx4 __attribute__((ext_vector_type(4)));
typedef u16 u16x4 __attribute__((ext_vector_type(4)));
typedef u16 u16x8 __attribute__((ext_vector_type(8)));

#define DEVI __device__ __forceinline__

DEVI u16 f2bf(float x) {
    union { float f; unsigned u; } c; c.f = x;
    unsigned u = c.u;
    u += 0x7fffu + ((u >> 16) & 1u);   // RNE
    return (u16)(u >> 16);
}
DEVI float bf2f(u16 h) {
    union { unsigned u; float f; } c; c.u = ((unsigned)h) << 16;
    return c.f;
}

DEVI void gload_lds16(const void* g, void* l) {
    auto gp = (const __attribute__((address_space(1))) unsigned*)(unsigned long long)g;
    auto lp = (__attribute__((address_space(3))) unsigned*)(unsigned)(unsigned long long)l;
    __builtin_amdgcn_global_load_lds(gp, lp, 16, 0, 0);
}

// ---------------- prep: weight conversions [0,1024) + fused GroupNorm [1024,1536) ----------------
__global__ __launch_bounds__(256) void prep_kernel(const float* __restrict__ w1, u16* __restrict__ o1,
                                                   const float* __restrict__ w2, u16* __restrict__ o2,
                                                   const float* __restrict__ x,
                                                   const float* __restrict__ gw,
                                                   const float* __restrict__ gb,
                                                   u16* __restrict__ h) {
    const int bid = blockIdx.x;
    if (bid < 1024) {
        int i = bid * 256 + threadIdx.x;   // of 262144 float4 slots
        const float* src; u16* dst; int j;
        if (i < 196608) { src = w1; dst = o1; j = i; }
        else            { src = w2; dst = o2; j = i - 196608; }
        float4 v = *(const float4*)&src[j * 4];
        u16x4 p; p[0] = f2bf(v.x); p[1] = f2bf(v.y); p[2] = f2bf(v.z); p[3] = f2bf(v.w);
        *(u16x4*)&dst[j * 4] = p;
        return;
    }
    // ---- GroupNorm: single global read, stats + apply in regs ----
    const int bg = bid - 1024;           // b*32+g
    const int b = bg >> 5, g = bg & 31;
    const float* xg = x + (long long)bg * 16384;
    const int n0 = threadIdx.x * 4;

    float4 xv[16];
    float s = 0.f, s2 = 0.f;
    #pragma unroll
    for (int cc = 0; cc < 16; cc++) {
        xv[cc] = *(const float4*)&xg[cc * 1024 + n0];
        s  += xv[cc].x + xv[cc].y + xv[cc].z + xv[cc].w;
        s2 += xv[cc].x*xv[cc].x + xv[cc].y*xv[cc].y + xv[cc].z*xv[cc].z + xv[cc].w*xv[cc].w;
    }
    #pragma unroll
    for (int m = 1; m < 64; m <<= 1) { s += __shfl_xor(s, m, 64); s2 += __shfl_xor(s2, m, 64); }
    __shared__ float rs[4], rq[4];
    if ((threadIdx.x & 63) == 0) { rs[threadIdx.x >> 6] = s; rq[threadIdx.x >> 6] = s2; }
    __syncthreads();
    float mean = (rs[0] + rs[1] + rs[2] + rs[3]) * (1.f / 16384.f);
    float var  = (rq[0] + rq[1] + rq[2] + rq[3]) * (1.f / 16384.f) - mean * mean;
    float rstd = rsqrtf(var + 1e-5f);

    u16x8 o[4][2];
    #pragma unroll
    for (int cc = 0; cc < 16; cc++) {
        int c = g * 16 + cc;
        float sc = gw[c] * rstd;
        float sh = gb[c] - mean * sc;
        o[0][cc >> 3][cc & 7] = f2bf(xv[cc].x * sc + sh);
        o[1][cc >> 3][cc & 7] = f2bf(xv[cc].y * sc + sh);
        o[2][cc >> 3][cc & 7] = f2bf(xv[cc].z * sc + sh);
        o[3][cc >> 3][cc & 7] = f2bf(xv[cc].w * sc + sh);
    }
    u16* hb = h + ((long long)b * 1024 + n0) * 512 + g * 16;
    #pragma unroll
    for (int k = 0; k < 4; k++) {
        *(u16x8*)&hb[(long long)k * 512]     = o[k][0];
        *(u16x8*)&hb[(long long)k * 512 + 8] = o[k][1];
    }
}

// ---------------- TN GEMM, 128x128 tile, BK=64 ----------------
// MODE 1: bf16 out, scaled ([m][n]); STATS: store E = exp(acc*scale) and emit per-row
//         partial sum(E) per key-block (softmax numerator + denominator in one pass)
// MODE 2: bf16 transposed out C0[n][m] + bias[m]
// MODE 3: fp32 out = acc*invl[n] + bias[m] + res. aux = psum; invl computed in-kernel
//         from the 8 per-key-block partials (lreduce folded in).
// NX>0: 1D launch, decoded so batch z runs on XCD z&7.
// MINW: min waves/SIMD for __launch_bounds__ (blocks/CU for 256-thread blocks).
template <int MODE, int NX, int NY, bool STATS, int MINW = 3>
__global__ __launch_bounds__(256, MINW)
void gemm_bt_kernel(const u16* __restrict__ A, const u16* __restrict__ Bt,
                    void* __restrict__ C0,
                    const float* __restrict__ bias, const float* __restrict__ res,
                    float* __restrict__ aux,
                    float scale, int lda, int ldb, int ldc,
                    long long sA, long long sB, long long sC, long long sR, int K) {
    int bx, by, bz;
    if (NX > 0) {
        const int lid  = blockIdx.x;
        const int xcd  = lid & 7;
        const int slot = lid >> 3;
        const int per  = NX * NY;
        const int j    = slot / per;
        const int w    = slot - j * per;
        bz = xcd + 8 * j;
        bx = w % NX;
        by = w / NX;
    } else {
        bx = blockIdx.x; by = blockIdx.y; bz = blockIdx.z;
    }
    const int t    = threadIdx.x;
    const int lane = t & 63;
    const int wave = t >> 6;
    const int m0   = by * 128;
    const int n0   = bx * 128;
    A  += (long long)bz * sA;
    Bt += (long long)bz * sB;

    __shared__ __align__(16) u16 smem[16384];   // 32 KB: A[2][128][32] | B[2][128][32]
    u16* As = smem;
    u16* Bs = smem + 8192;

    const int wm = wave >> 1, wn = wave & 1;
    const int quad = lane >> 4, lrow = lane & 15;

    floatx4 acc[4][4];
    #pragma unroll
    for (int i = 0; i < 4; i++)
        #pragma unroll
        for (int j = 0; j < 4; j++)
            #pragma unroll
            for (int r = 0; r < 4; r++) acc[i][j][r] = 0.f;

    const int rowA = t >> 2;
    const int kch  = (t & 3) * 8;
    const u16* Ag = A  + (long long)(m0 + rowA) * lda + kch;
    const u16* Bg = Bt + (long long)(n0 + rowA) * ldb + kch;
    u16* Al = &As[t * 8];
    u16* Bl = &Bs[t * 8];
    const long long a64 = (long long)64 * lda;
    const long long b64 = (long long)64 * ldb;

    for (int k0 = 0; k0 < K; k0 += 64) {
        gload_lds16(Ag + k0,            Al);
        gload_lds16(Ag + k0 + a64,      Al + 2048);
        gload_lds16(Ag + k0 + 32,       Al + 4096);
        gload_lds16(Ag + k0 + 32 + a64, Al + 6144);
        gload_lds16(Bg + k0,            Bl);
        gload_lds16(Bg + k0 + b64,      Bl + 2048);
        gload_lds16(Bg + k0 + 32,       Bl + 4096);
        gload_lds16(Bg + k0 + 32 + b64, Bl + 6144);
        __syncthreads();
        #pragma unroll
        for (int kk = 0; kk < 2; kk++) {
            short8 af[4], bfr[4];
            #pragma unroll
            for (int i = 0; i < 4; i++)
                af[i] = *(const short8*)&As[kk*4096 + (wm*64 + i*16 + lrow)*32 + quad*8];
            #pragma unroll
            for (int j = 0; j < 4; j++)
                bfr[j] = *(const short8*)&Bs[kk*4096 + (wn*64 + j*16 + lrow)*32 + quad*8];
            #pragma unroll
            for (int i = 0; i < 4; i++)
                #pragma unroll
                for (int j = 0; j < 4; j++)
                    acc[i][j] = __builtin_amdgcn_mfma_f32_16x16x32_bf16(af[i], bfr[j], acc[i][j], 0, 0, 0);
        }
        __syncthreads();
    }
    // smem free from here

    const int ST = 136;  // u16 row stride (272 B = 17*16)

    if (MODE == 1) {
        #pragma unroll
        for (int p = 0; p < 4; p++) {
            if (p) __syncthreads();
            if (wm == (p >> 1)) {
                #pragma unroll
                for (int ii = 0; ii < 2; ii++) {
                    const int i = (p & 1) * 2 + ii;
                    const int row = ii * 16 + quad * 4;
                    #pragma unroll
                    for (int j = 0; j < 4; j++) {
                        const int cB = wn * 64 + j * 16 + lrow;
                        #pragma unroll
                        for (int r = 0; r < 4; r++) {
                            float v = acc[i][j][r] * scale;
                            if (STATS) v = __expf(v);          // store E = exp(S*scale)
                            smem[(row + r) * ST + cB] = f2bf(v);
                        }
                    }
                }
            }
            __syncthreads();
            const int rr = t >> 3, cc = (t & 7) * 16;
            u16x8 a0 = *(u16x8*)&smem[rr * ST + cc];
            u16x8 a1 = *(u16x8*)&smem[rr * ST + cc + 8];
            u16* Cp = (u16*)C0 + (long long)bz * sC + (long long)(m0 + p * 32 + rr) * ldc + n0 + cc;
            *(u16x8*)Cp = a0;
            *(u16x8*)(Cp + 8) = a1;
            if (STATS) {
                // partial sum of E over this block's 128 key-cols, per query row
                // (sums the SAME bf16 values used as the softmax numerator)
                float ls = 0.f;
                #pragma unroll
                for (int e = 0; e < 8; e++)
                    ls += bf2f(a0[e]) + bf2f(a1[e]);
                #pragma unroll
                for (int m2 = 1; m2 < 8; m2 <<= 1) ls += __shfl_xor(ls, m2, 8);
                if ((t & 7) == 0)
                    aux[((long long)(bz * 8 + bx)) * 1024 + m0 + p * 32 + rr] = ls;
            }
        }
    } else if (MODE == 2) {
        #pragma unroll
        for (int p = 0; p < 4; p++) {
            if (p) __syncthreads();
            if (wn == (p >> 1)) {
                #pragma unroll
                for (int jj = 0; jj < 2; jj++) {
                    const int j = (p & 1) * 2 + jj;
                    const int row = jj * 16 + lrow;
                    #pragma unroll
                    for (int i = 0; i < 4; i++) {
                        const int mmL = wm * 64 + i * 16 + quad * 4;
                        u16x4 pk;
                        #pragma unroll
                        for (int r = 0; r < 4; r++)
                            pk[r] = f2bf(acc[i][j][r] + bias[m0 + mmL + r]);
                        *(u16x4*)&smem[row * ST + mmL] = pk;
                    }
                }
            }
            __syncthreads();
            const int rr = t >> 3, cc = (t & 7) * 16;
            u16x8 a0 = *(u16x8*)&smem[rr * ST + cc];
            u16x8 a1 = *(u16x8*)&smem[rr * ST + cc + 8];
            u16* Cp = (u16*)C0 + (long long)(n0 + p * 32 + rr) * ldc + m0 + cc;
            *(u16x8*)Cp = a0;
            *(u16x8*)(Cp + 8) = a1;
        }
    } else {
        // MODE 3: fp32 out = acc*invl[col] + bias[row] + res ; invl from psum in-kernel
        __shared__ float sinv[128];
        if (t < 128) {
            const float* pz = aux + ((long long)bz * 8) * 1024 + n0 + t;
            float l = 0.f;
            #pragma unroll
            for (int kb = 0; kb < 8; kb++) l += pz[(long long)kb * 1024];
            sinv[t] = 1.f / l;
        }
        float* smf = (float*)smem;
        const int SF = 132;
        float* C = (float*)C0 + (long long)bz * sC;
        const float* rz = res + (long long)bz * sR;
        #pragma unroll
        for (int p = 0; p < 8; p++) {
            if (p) __syncthreads();
            if (wm == (p >> 2)) {
                const int i = p & 3;
                #pragma unroll
                for (int j = 0; j < 4; j++) {
                    const int cB = wn * 64 + j * 16 + lrow;
                    #pragma unroll
                    for (int r = 0; r < 4; r++)
                        smf[(quad * 4 + r) * SF + cB] = acc[i][j][r];
                }
            }
            __syncthreads();   // orders sinv writes (p=0) and smf writes before reads
            const int rr = t >> 4, cc = (t & 15) * 8;
            const float bsv = bias[m0 + p * 16 + rr];
            float4 il0 = *(const float4*)&sinv[cc];
            float4 il1 = *(const float4*)&sinv[cc + 4];
            const long long gro = (long long)(m0 + p * 16 + rr) * ldc + n0 + cc;
            float4 rv0 = *(const float4*)&rz[gro];
            float4 rv1 = *(const float4*)&rz[gro + 4];
            float4 ov0, ov1;
            ov0.x = smf[rr*SF + cc + 0] * il0.x + bsv + rv0.x;
            ov0.y = smf[rr*SF + cc + 1] * il0.y + bsv + rv0.y;
            ov0.z = smf[rr*SF + cc + 2] * il0.z + bsv + rv0.z;
            ov0.w = smf[rr*SF + cc + 3] * il0.w + bsv + rv0.w;
            ov1.x = smf[rr*SF + cc + 4] * il1.x + bsv + rv1.x;
            ov1.y = smf[rr*SF + cc + 5] * il1.y + bsv + rv1.y;
            ov1.z = smf[rr*SF + cc + 6] * il1.z + bsv + rv1.z;
            ov1.w = smf[rr*SF + cc + 7] * il1.w + bsv + rv1.w;
            *(float4*)&C[gro]     = ov0;
            *(float4*)&C[gro + 4] = ov1;
        }
    }
}

extern "C" void kernel_launch(void* const* d_in, const int* in_sizes, int n_in,
                              void* d_out, int out_size, void* d_ws, size_t ws_size,
                              hipStream_t stream) {
    (void)in_sizes; (void)n_in; (void)out_size; (void)ws_size;
    const float* x     = (const float*)d_in[0];
    const float* gn_w  = (const float*)d_in[1];
    const float* gn_b  = (const float*)d_in[2];
    const float* qkv_w = (const float*)d_in[3];
    const float* qkv_b = (const float*)d_in[4];
    const float* out_w = (const float*)d_in[5];
    const float* out_b = (const float*)d_in[6];
    float* out = (float*)d_out;

    char* ws = (char*)d_ws;
    u16*  h_t   = (u16*)ws;  ws += (size_t)16*1024*512*2;    // 16 MB h[b][n][c]
    u16*  qkv_t = (u16*)ws;  ws += (size_t)16*1024*1536*2;   // 48 MB qkv[b*n][1536]
    u16*  vprm  = (u16*)ws;  ws += (size_t)512*16384*2;      // 16 MB V' = Wo V^T : [c_out][b*1024+n]
    u16*  E     = (u16*)ws;  ws += (size_t)16*1024*1024*2;   // 32 MB E[b][n][m] = exp(S*scale), bf16
    u16*  wq    = (u16*)ws;  ws += (size_t)1536*512*2;
    u16*  wo    = (u16*)ws;  ws += (size_t)512*512*2;
    float* psum = (float*)ws; ws += (size_t)16*8*1024*4;     // partial sum(E) per key-block

    // weight conversion + GroupNorm in one launch
    prep_kernel<<<1536, 256, 0, stream>>>(qkv_w, wq, out_w, wo, x, gn_w, gn_b, h_t);

    // QKV: M=1536, Nn=16384, K=512 ; all transposed -> qkv_t[bn][1536] + bias
    // 1536 blocks = exactly 2 full rounds at 3 blocks/CU.
    gemm_bt_kernel<2, 0, 0, false, 3><<<dim3(128, 12, 1), 256, 0, stream>>>(
        wq, h_t, qkv_t, qkv_b, nullptr, nullptr, 1.0f,
        512, 512, 1536, 0, 0, 0, 0, 512);

    // V' = Wo @ V^T : M=512(c_out), Nn=16384(bn), K=512(c_in)
    gemm_bt_kernel<1, 0, 0, false, 3><<<dim3(128, 4, 1), 256, 0, stream>>>(
        wo, qkv_t + 1024, vprm, nullptr, nullptr, nullptr, 1.0f,
        512, 1536, 16384, 0, 0, 0, 0, 512);

    // E = exp(q k^T * scale) : per batch M=Nn=1024, K=512 ; XCD-affine + partial sum(E) stats
    // 1024 blocks = exactly 1 full round at 4 blocks/CU.
    gemm_bt_kernel<1, 8, 8, true, 4><<<1024, 256, 0, stream>>>(
        qkv_t, qkv_t + 512, E, nullptr, nullptr, psum, 0.044194173824159216f,
        1536, 1536, 1024,
        (long long)1024*1536, (long long)1024*1536, (long long)1024*1024, 0, 512);

    // out = vprm ⊗ E * invl + out_b + x : M=512, Nn=1024(n), K=1024(m) ; XCD-affine,
    // plain DMA B, invl computed in-kernel from psum (lreduce folded in)
    gemm_bt_kernel<3, 8, 4, false, 3><<<512, 256, 0, stream>>>(
        vprm, E, out, out_b, x, psum, 1.0f,
        16384, 1024, 1024,
        1024, (long long)1024*1024, (long long)512*1024, (long long)512*1024, 1024);
}